// Round 19
// baseline (134.394 us; speedup 1.0000x reference)
//
#include <hip/hip_runtime.h>
#include <hip/hip_bf16.h>

typedef unsigned short u16;
typedef unsigned int u32;
typedef __bf16 bf16x8 __attribute__((ext_vector_type(8)));
typedef float f32x4 __attribute__((ext_vector_type(4)));
typedef float f32x16 __attribute__((ext_vector_type(16)));

#define B_  8
#define N_  4096
#define D_  32
#define CV_ 256
#define LOG2E 1.442695040888963f

#define MFMA16 __builtin_amdgcn_mfma_f32_16x16x32_bf16
#define MFMA32 __builtin_amdgcn_mfma_f32_32x32x16_bf16

static __device__ __forceinline__ u16 f2bf(float x) {
    union { float f; unsigned int u; } v; v.f = x;
    unsigned int r = (v.u + 0x7FFFu + ((v.u >> 16) & 1u)) >> 16;
    return (u16)r;
}

// raw v_exp_f32: D = 2^S0 (single trans-op; avoids OCML exp2f subnormal fixup libcall)
static __device__ __forceinline__ float fexp2(float x) {
    float r;
    asm("v_exp_f32 %0, %1" : "=v"(r) : "v"(x));
    return r;
}

static __device__ __forceinline__ void gload16(const u16* g, u16* l) {
    __builtin_amdgcn_global_load_lds(
        (const __attribute__((address_space(1))) unsigned int*)g,
        (__attribute__((address_space(3))) unsigned int*)l, 16, 0, 0);
}
static __device__ __forceinline__ void gload4(const u16* g, u16* l) {
    __builtin_amdgcn_global_load_lds(
        (const __attribute__((address_space(1))) unsigned int*)g,
        (__attribute__((address_space(3))) unsigned int*)l, 4, 0, 0);
}

// ---------------- W convert kernel (Wf scaled by log2e for exp2-softmax) ----------------
__global__ void wcvt_kernel(const float* __restrict__ Wf, const float* __restrict__ Wg,
                            const float* __restrict__ Wh,
                            u16* __restrict__ wfb, u16* __restrict__ wgb, u16* __restrict__ whb)
{
    int i = (blockIdx.x * 256 + threadIdx.x) * 4;
    const float* src; u16* dst; float sc = 1.0f;
    if (i < 8192)       { src = Wf + i;         dst = wfb + i; sc = LOG2E; }
    else if (i < 16384) { src = Wg + i - 8192;  dst = wgb + i - 8192; }
    else                { src = Wh + i - 16384; dst = whb + i - 16384; }
    float4 v = *(const float4*)src;
    ushort4 o; o.x = f2bf(v.x*sc); o.y = f2bf(v.y*sc); o.z = f2bf(v.z*sc); o.w = f2bf(v.w*sc);
    *(ushort4*)dst = o;
}

// ---------------- projection kernel (MFMA 16x16x32) ----------------
// Outputs:
//   fbuf [b][n][32]                          (log2e-scaled Q rows, plain)
//   gbuf [b][kt][kv][slot^((kv>>1)&3)][8]    (K, kv-tiled, batch-spread swizzle)
//   hbuf [b][kt][c][slot^((c>>1)&3)][8]      (V^T, kv-tiled, batch-spread swizzle)
__global__ __launch_bounds__(512, 4)
void proj_kernel(const float* __restrict__ q, const float* __restrict__ kv,
                 const u16* __restrict__ wfb, const float* __restrict__ pbf,
                 const u16* __restrict__ wgb, const float* __restrict__ pbg,
                 const u16* __restrict__ whb, const float* __restrict__ pbh,
                 u16* __restrict__ fbuf, u16* __restrict__ gbuf, u16* __restrict__ hbuf)
{
    __shared__ __align__(16) u16 xq[64][256];
    __shared__ __align__(16) u16 xk[64][256];
    const int b  = blockIdx.x & 7;
    const int n0 = (blockIdx.x >> 3) * 64;
    const int t  = threadIdx.x;
    const int w  = t >> 6, lane = t & 63, lg = lane >> 4, lc = lane & 15;
    const size_t bb = (size_t)b * CV_ * N_;
    const f32x4 zf = {0.f, 0.f, 0.f, 0.f};

    {
        int n = t & 63, cg = t >> 6;
        for (int p = 0; p < 16; p++) {
            int c = (p * 8 + cg) * 2;
            const float* qp = q  + bb + (size_t)c * N_ + n0 + n;
            const float* kp = kv + bb + (size_t)c * N_ + n0 + n;
            float q0v = qp[0], q1v = qp[N_];
            float k0v = kp[0], k1v = kp[N_];
            int idx = (((c >> 3) ^ (n & 7)) * 8) + (c & 7);
            *(unsigned*)&xq[n][idx] = (unsigned)f2bf(q0v) | ((unsigned)f2bf(q1v) << 16);
            *(unsigned*)&xk[n][idx] = (unsigned)f2bf(k0v) | ((unsigned)f2bf(k1v) << 16);
        }
    }
    __syncthreads();

    {
        const u16*  wsel = (w < 4) ? wfb : wgb;
        const float* bsel = (w < 4) ? pbf : pbg;
        const float bscale = (w < 4) ? LOG2E : 1.0f;
        const u16 (*xs)[256] = (w < 4) ? (const u16(*)[256])xq : (const u16(*)[256])xk;
        const int nch = w & 3;
        f32x4 acc[2] = {zf, zf};
#pragma unroll
        for (int kk = 0; kk < 8; kk++) {
            bf16x8 a = *(const bf16x8*)&xs[nch*16 + lc][((kk*4 + lg) ^ (lc & 7)) * 8];
#pragma unroll
            for (int bt = 0; bt < 2; bt++) {
                bf16x8 bw = *(const bf16x8*)&wsel[(size_t)(bt*16 + lc) * 256 + kk*32 + lg*8];
                acc[bt] = MFMA16(a, bw, acc[bt], 0, 0, 0);
            }
        }
        if (w < 4) {
#pragma unroll
            for (int bt = 0; bt < 2; bt++) {
                float bias = bsel[bt*16 + lc] * bscale;
#pragma unroll
                for (int r = 0; r < 4; r++) {
                    int n = n0 + nch*16 + lg*4 + r;
                    fbuf[((size_t)b * N_ + n) * D_ + bt*16 + lc] = f2bf(acc[bt][r] + bias);
                }
            }
        } else {
#pragma unroll
            for (int bt = 0; bt < 2; bt++) {
                float bias = bsel[bt*16 + lc];
                int dk = bt*16 + lc;
#pragma unroll
                for (int r = 0; r < 4; r++) {
                    int n = n0 + nch*16 + lg*4 + r;
                    size_t off = ((size_t)b*128 + (n>>5))*1024 + (size_t)(n&31)*32
                               + ((((dk>>3)&3) ^ ((n>>1)&3)) << 3) + (dk&7);
                    gbuf[off] = f2bf(acc[bt][r] + bias);
                }
            }
        }
    }

    {
        const int cw = w * 32;
        f32x4 acch[2][4];
#pragma unroll
        for (int ct = 0; ct < 2; ct++)
#pragma unroll
            for (int nt = 0; nt < 4; nt++) acch[ct][nt] = zf;
#pragma unroll
        for (int kk = 0; kk < 8; kk++) {
            bf16x8 ah[2];
#pragma unroll
            for (int ct = 0; ct < 2; ct++)
                ah[ct] = *(const bf16x8*)&whb[(size_t)(cw + ct*16 + lc) * 256 + kk*32 + lg*8];
#pragma unroll
            for (int nt = 0; nt < 4; nt++) {
                bf16x8 bx = *(const bf16x8*)&xk[nt*16 + lc][((kk*4 + lg) ^ (lc & 7)) * 8];
#pragma unroll
                for (int ct = 0; ct < 2; ct++)
                    acch[ct][nt] = MFMA16(ah[ct], bx, acch[ct][nt], 0, 0, 0);
            }
        }
#pragma unroll
        for (int ct = 0; ct < 2; ct++)
#pragma unroll
            for (int r = 0; r < 4; r++) {
                int c = cw + ct*16 + lg*4 + r;
                float bias = pbh[c];
#pragma unroll
                for (int nt = 0; nt < 4; nt++) {
                    int n = n0 + nt*16 + lc;
                    size_t off = ((size_t)b*128 + (n>>5))*8192 + (size_t)c*32
                               + ((((n>>3)&3) ^ ((c>>1)&3)) << 3) + (n&7);
                    hbuf[off] = f2bf(acch[ct][nt][r] + bias);
                }
            }
    }
}

// ---------------- flash attention kernel (parity split + PV pipeline + PHASE STAGGER) ----------------
// grid 256 (b = blk&7, q0 = (blk>>3)*128), 512 threads = 8 waves:
// qw = w&3 (32 q-rows), par = w>>2 (tile parity; own tiles t = 2p+par).
// Waves w and w+4 (par 0/1) share a SIMD. Window body is PHASE-STAGGERED by parity:
//   par=0: K-read+QK -> PV(prev) -> exp_pack -> stage
//   par=1: PV(prev) -> K-read+QK -> exp_pack -> stage
// so one wave issues PV MFMAs (register+resident-V) while the other waits on
// K-lgkm/QK, and vice versa -- complementary pipe usage instead of phase-aligned
// collisions. PV(prev) uses pa from the previous own tile with V from tile (t-2)'s
// still-resident buffer (r18 deferral). Stages at END of window; vmcnt(6) => 12 loads
// in flight at each barrier, 6 drained. p=0 reads V from tile t itself (pa_old==0).
// Tail: final PV from buffers 6/7 (never overwritten; dummy stages land in 0-3).
__global__ __launch_bounds__(512, 2)
void attn_kernel(const u16* __restrict__ fbuf, const u16* __restrict__ gbuf,
                 const u16* __restrict__ hbuf, const float* __restrict__ kvp,
                 const float* __restrict__ gamma_p, float* __restrict__ out)
{
    __shared__ __align__(16) u16 smem[8 * 9216];   // 8 x (V 16KB + K 2KB) = 144 KB

    const int b  = blockIdx.x & 7;
    const int q0 = (blockIdx.x >> 3) * 128;
    const int t  = threadIdx.x;
    const int w  = t >> 6;
    const int l  = t & 63;
    const int qw = w & 3;
    const int par = w >> 2;          // tile parity; waves w, w+4 share a SIMD
    const int lr = l & 31;
    const int b5 = l >> 5;
    const int sw = (lr >> 1) & 3;

    const u16* hb_t = hbuf + (size_t)b * 128 * 8192;
    const u16* gb_t = gbuf + (size_t)b * 128 * 1024;

    bf16x8 qf0, qf1;
    {
        const u16* fb = fbuf + ((size_t)b * N_ + q0 + qw*32 + lr) * D_;
        qf0 = *(const bf16x8*)(fb + b5*8);
        qf1 = *(const bf16x8*)(fb + 16 + b5*8);
    }

    bf16x8 ones, pa_old0, pa_old1;
    {
        union { u32 u[4]; bf16x8 v; } ov;
        ov.u[0] = 0x3F803F80u; ov.u[1] = 0x3F803F80u;
        ov.u[2] = 0x3F803F80u; ov.u[3] = 0x3F803F80u;
        ones = ov.v;
        union { u32 u[4]; bf16x8 v; } zv;
        zv.u[0] = 0; zv.u[1] = 0; zv.u[2] = 0; zv.u[3] = 0;
        pa_old0 = zv.v; pa_old1 = zv.v;
    }

    const f32x16 zf16 = {0,0,0,0, 0,0,0,0, 0,0,0,0, 0,0,0,0};
    f32x16 o_acc[8] = {zf16, zf16, zf16, zf16, zf16, zf16, zf16, zf16};
    f32x16 o_den = zf16;             // per-parity denominator (ones-B MFMA)

    const int koff0 = lr*32 + (((0|b5) ^ sw) << 3);
    const int koff1 = lr*32 + (((2|b5) ^ sw) << 3);
    const int vbase = lr*32;         // all 256 channels: + ct*1024 + vph
    const int vph0  = ((0|b5) ^ sw) << 3;
    const int vph1  = ((2|b5) ^ sw) << 3;

    auto stage = [&](int nb, int kt) {
        const u16* sv = hb_t + (size_t)kt*8192 + t*8;
        u16* dv = smem + nb*9216 + t*8;
        gload16(sv, dv);
        gload16(sv + 4096, dv + 4096);
        gload4(gb_t + (size_t)kt*1024 + t*2, smem + nb*9216 + 8192 + t*2);
    };

    // static softmax: P = exp2(s) in place, pack to bf16 A-fragments (r13-validated)
    auto exp_pack = [&](f32x16& s, bf16x8& pa0, bf16x8& pa1) {
#pragma unroll
        for (int i = 0; i < 16; ++i) s[i] = fexp2(s[i]);
#pragma unroll
        for (int kc = 0; kc < 2; ++kc) {
            u32 d0, d1, e0, e1;
            { __hip_bfloat162 h2 = __float22bfloat162_rn(make_float2(s[8*kc+0], s[8*kc+1])); d0 = *(u32*)&h2; }
            { __hip_bfloat162 h2 = __float22bfloat162_rn(make_float2(s[8*kc+2], s[8*kc+3])); d1 = *(u32*)&h2; }
            { __hip_bfloat162 h2 = __float22bfloat162_rn(make_float2(s[8*kc+4], s[8*kc+5])); e0 = *(u32*)&h2; }
            { __hip_bfloat162 h2 = __float22bfloat162_rn(make_float2(s[8*kc+6], s[8*kc+7])); e1 = *(u32*)&h2; }
            asm("v_permlane32_swap_b32 %0, %1" : "+v"(d0), "+v"(e0));
            asm("v_permlane32_swap_b32 %0, %1" : "+v"(d1), "+v"(e1));
            union { u32 u[4]; bf16x8 v; } pk;
            pk.u[0] = d0; pk.u[1] = d1; pk.u[2] = e0; pk.u[3] = e1;
            if (kc == 0) pa0 = pk.v; else pa1 = pk.v;
        }
    };

    // PV + denominator with given pa pair, V from buffer nbv
    auto pv_den = [&](int nbv, bf16x8 pa0, bf16x8 pa1) {
        const u16* Vl = smem + nbv*9216;
        __builtin_amdgcn_s_setprio(1);
        o_den = MFMA32(pa0, ones, o_den, 0, 0, 0);
        o_den = MFMA32(pa1, ones, o_den, 0, 0, 0);
#pragma unroll
        for (int ct = 0; ct < 8; ++ct) {
            bf16x8 v0 = *(const bf16x8*)(Vl + vbase + ct*1024 + vph0);
            bf16x8 v1 = *(const bf16x8*)(Vl + vbase + ct*1024 + vph1);
            o_acc[ct] = MFMA32(pa0, v0, o_acc[ct], 0, 0, 0);
            o_acc[ct] = MFMA32(pa1, v1, o_acc[ct], 0, 0, 0);
        }
        __builtin_amdgcn_s_setprio(0);
    };

    // QK for tile kt (K read + 2 MFMA)
    auto qk = [&](int kt, f32x16& s) {
        const u16* Kl = smem + (kt & 7)*9216 + 8192;
        bf16x8 kf0 = *(const bf16x8*)(Kl + koff0);
        bf16x8 kf1 = *(const bf16x8*)(Kl + koff1);
        __builtin_amdgcn_s_setprio(1);
        s = MFMA32(kf0, qf0, zf16, 0, 0, 0);
        s = MFMA32(kf1, qf1, s, 0, 0, 0);
        __builtin_amdgcn_s_setprio(0);
    };

    stage(0, 0); stage(1, 1); stage(2, 2); stage(3, 3);   // 12 loads

    for (int p = 0; p < 64; ++p) {
        // tiles 2p,2p+1 landed (6 loads from end of window p-1 stay in flight)
        asm volatile("s_waitcnt vmcnt(6)\n\ts_barrier" ::: "memory");

        const int kt = 2*p + par;                         // own-parity tile
        const int tv = (p == 0) ? kt : kt - 2;            // deferred-PV V source
        f32x16 s;

        if (par == 0) {
            // par 0: QK first, PV second
            qk(kt, s);
            pv_den(tv & 7, pa_old0, pa_old1);
        } else {
            // par 1: PV first, QK second (phase-staggered vs par 0)
            pv_den(tv & 7, pa_old0, pa_old1);
            qk(kt, s);
        }

        exp_pack(s, pa_old0, pa_old1);

        // stage next tiles at END of window (gives deferred-V reads barrier safety)
        int ta = 2*p + 4; if (ta > 127) ta = 127;         // dummy re-stage in tail
        int tb = 2*p + 5; if (tb > 127) tb = 127;
        stage((2*p + 4) & 7, ta);
        stage((2*p + 5) & 7, tb);
    }

    // tail: PV of the last own tile (126+par, buffers 6/7 -- never overwritten)
    pv_den((126 + par) & 7, pa_old0, pa_old1);

    // ---- epilogue (drain dummy prefetches; sync before smem reuse -- lbuf overlaps buf 6/7)
    asm volatile("s_waitcnt vmcnt(0)" ::: "memory");
    __syncthreads();
    const float gmm = gamma_p[0];

    // l-exchange across parity: lbuf [2 par][4 qw][64 lane][16 g] f32 = 32 KB
    float* lbuf = (float*)smem;
    {
        float* myl = lbuf + (((par*4 + qw)*64 + l) * 16);
        *(f32x4*)(myl +  0) = (f32x4){o_den[0],  o_den[1],  o_den[2],  o_den[3]};
        *(f32x4*)(myl +  4) = (f32x4){o_den[4],  o_den[5],  o_den[6],  o_den[7]};
        *(f32x4*)(myl +  8) = (f32x4){o_den[8],  o_den[9],  o_den[10], o_den[11]};
        *(f32x4*)(myl + 12) = (f32x4){o_den[12], o_den[13], o_den[14], o_den[15]};
    }
    __syncthreads();
    float linv[16];
    {
        const float* pl = lbuf + ((((par^1)*4 + qw)*64 + l) * 16);
#pragma unroll
        for (int g = 0; g < 16; ++g) linv[g] = gmm / (o_den[g] + pl[g]);
    }

    float* o_trA = (float*)smem;          // [64 c][132 q] f32 = 33792 B
    float* o_trB = o_trA + 64*132;        // parity-1 partial
    for (int cc = 0; cc < 4; ++cc) {
        __syncthreads();                   // also separates lbuf reads from o_trA writes
        float* buf = par ? o_trB : o_trA;
#pragma unroll
        for (int ci = 0; ci < 2; ++ci) {
            int ct = cc*2 + ci;
#pragma unroll
            for (int g = 0; g < 16; ++g) {
                int q_loc = (g & 3) + 8*(g >> 2) + b5*4;
                buf[(ci*32 + lr)*132 + qw*32 + q_loc] = o_acc[ct][g] * linv[g];
            }
        }
        __syncthreads();
        int c_loc = t >> 3, j = t & 7;
        int c = cc*64 + c_loc;
        size_t base = ((size_t)b*CV_ + c)*N_ + q0 + j*16;
        const float* oa = o_trA + c_loc*132 + j*16;
        const float* ob = o_trB + c_loc*132 + j*16;
#pragma unroll
        for (int u = 0; u < 4; ++u) {
            float4 kvv = *(const float4*)(kvp + base + u*4);
            float4 rs;
            rs.x = oa[u*4+0] + ob[u*4+0] + kvv.x;
            rs.y = oa[u*4+1] + ob[u*4+1] + kvv.y;
            rs.z = oa[u*4+2] + ob[u*4+2] + kvv.z;
            rs.w = oa[u*4+3] + ob[u*4+3] + kvv.w;
            *(float4*)(out + base + u*4) = rs;
        }
    }
}

extern "C" void kernel_launch(void* const* d_in, const int* in_sizes, int n_in,
                              void* d_out, int out_size, void* d_ws, size_t ws_size,
                              hipStream_t stream)
{
    const float* q     = (const float*)d_in[0];
    const float* kv    = (const float*)d_in[1];
    const float* Wf    = (const float*)d_in[2];
    const float* pbf   = (const float*)d_in[3];
    const float* Wg    = (const float*)d_in[4];
    const float* pbg   = (const float*)d_in[5];
    const float* Wh    = (const float*)d_in[6];
    const float* pbh   = (const float*)d_in[7];
    const float* gamma = (const float*)d_in[8];
    float* out = (float*)d_out;

    u16* wfb  = (u16*)d_ws;
    u16* wgb  = wfb + 8192;
    u16* whb  = wgb + 8192;
    u16* fbuf = whb + 65536;
    u16* gbuf = fbuf + (size_t)B_ * N_ * D_;
    u16* hbuf = gbuf + (size_t)B_ * N_ * D_;

    wcvt_kernel<<<dim3(80), dim3(256), 0, stream>>>(Wf, Wg, Wh, wfb, wgb, whb);
    proj_kernel<<<dim3(512), dim3(512), 0, stream>>>(q, kv, wfb, pbf, wgb, pbg, whb, pbh,
                                                     fbuf, gbuf, hbuf);
    attn_kernel<<<dim3(256), dim3(512), 0, stream>>>(fbuf, gbuf, hbuf, kv, gamma, out);
}

// Round 20
// 132.569 us; speedup vs baseline: 1.0138x; 1.0138x over previous
//
#include <hip/hip_runtime.h>
#include <hip/hip_bf16.h>

typedef unsigned short u16;
typedef unsigned int u32;
typedef __bf16 bf16x8 __attribute__((ext_vector_type(8)));
typedef float f32x4 __attribute__((ext_vector_type(4)));
typedef float f32x16 __attribute__((ext_vector_type(16)));

#define B_  8
#define N_  4096
#define D_  32
#define CV_ 256
#define LOG2E 1.442695040888963f

#define MFMA16 __builtin_amdgcn_mfma_f32_16x16x32_bf16
#define MFMA32 __builtin_amdgcn_mfma_f32_32x32x16_bf16

static __device__ __forceinline__ u16 f2bf(float x) {
    union { float f; unsigned int u; } v; v.f = x;
    unsigned int r = (v.u + 0x7FFFu + ((v.u >> 16) & 1u)) >> 16;
    return (u16)r;
}

// raw v_exp_f32: D = 2^S0 (single trans-op; avoids OCML exp2f subnormal fixup libcall)
static __device__ __forceinline__ float fexp2(float x) {
    float r;
    asm("v_exp_f32 %0, %1" : "=v"(r) : "v"(x));
    return r;
}

static __device__ __forceinline__ void gload16(const u16* g, u16* l) {
    __builtin_amdgcn_global_load_lds(
        (const __attribute__((address_space(1))) unsigned int*)g,
        (__attribute__((address_space(3))) unsigned int*)l, 16, 0, 0);
}
static __device__ __forceinline__ void gload4(const u16* g, u16* l) {
    __builtin_amdgcn_global_load_lds(
        (const __attribute__((address_space(1))) unsigned int*)g,
        (__attribute__((address_space(3))) unsigned int*)l, 4, 0, 0);
}

// ---------------- W convert kernel (Wf scaled by log2e for exp2-softmax) ----------------
__global__ void wcvt_kernel(const float* __restrict__ Wf, const float* __restrict__ Wg,
                            const float* __restrict__ Wh,
                            u16* __restrict__ wfb, u16* __restrict__ wgb, u16* __restrict__ whb)
{
    int i = (blockIdx.x * 256 + threadIdx.x) * 4;
    const float* src; u16* dst; float sc = 1.0f;
    if (i < 8192)       { src = Wf + i;         dst = wfb + i; sc = LOG2E; }
    else if (i < 16384) { src = Wg + i - 8192;  dst = wgb + i - 8192; }
    else                { src = Wh + i - 16384; dst = whb + i - 16384; }
    float4 v = *(const float4*)src;
    ushort4 o; o.x = f2bf(v.x*sc); o.y = f2bf(v.y*sc); o.z = f2bf(v.z*sc); o.w = f2bf(v.w*sc);
    *(ushort4*)dst = o;
}

// ---------------- projection kernel (MFMA 16x16x32) ----------------
// Outputs:
//   fbuf [b][n][32]                          (log2e-scaled Q rows, plain)
//   gbuf [b][kt][kv][slot^((kv>>1)&3)][8]    (K, kv-tiled, batch-spread swizzle)
//   hbuf [b][kt][c][slot^((c>>1)&3)][8]      (V^T, kv-tiled, batch-spread swizzle)
__global__ __launch_bounds__(512, 4)
void proj_kernel(const float* __restrict__ q, const float* __restrict__ kv,
                 const u16* __restrict__ wfb, const float* __restrict__ pbf,
                 const u16* __restrict__ wgb, const float* __restrict__ pbg,
                 const u16* __restrict__ whb, const float* __restrict__ pbh,
                 u16* __restrict__ fbuf, u16* __restrict__ gbuf, u16* __restrict__ hbuf)
{
    __shared__ __align__(16) u16 xq[64][256];
    __shared__ __align__(16) u16 xk[64][256];
    const int b  = blockIdx.x & 7;
    const int n0 = (blockIdx.x >> 3) * 64;
    const int t  = threadIdx.x;
    const int w  = t >> 6, lane = t & 63, lg = lane >> 4, lc = lane & 15;
    const size_t bb = (size_t)b * CV_ * N_;
    const f32x4 zf = {0.f, 0.f, 0.f, 0.f};

    {
        int n = t & 63, cg = t >> 6;
        for (int p = 0; p < 16; p++) {
            int c = (p * 8 + cg) * 2;
            const float* qp = q  + bb + (size_t)c * N_ + n0 + n;
            const float* kp = kv + bb + (size_t)c * N_ + n0 + n;
            float q0v = qp[0], q1v = qp[N_];
            float k0v = kp[0], k1v = kp[N_];
            int idx = (((c >> 3) ^ (n & 7)) * 8) + (c & 7);
            *(unsigned*)&xq[n][idx] = (unsigned)f2bf(q0v) | ((unsigned)f2bf(q1v) << 16);
            *(unsigned*)&xk[n][idx] = (unsigned)f2bf(k0v) | ((unsigned)f2bf(k1v) << 16);
        }
    }
    __syncthreads();

    {
        const u16*  wsel = (w < 4) ? wfb : wgb;
        const float* bsel = (w < 4) ? pbf : pbg;
        const float bscale = (w < 4) ? LOG2E : 1.0f;
        const u16 (*xs)[256] = (w < 4) ? (const u16(*)[256])xq : (const u16(*)[256])xk;
        const int nch = w & 3;
        f32x4 acc[2] = {zf, zf};
#pragma unroll
        for (int kk = 0; kk < 8; kk++) {
            bf16x8 a = *(const bf16x8*)&xs[nch*16 + lc][((kk*4 + lg) ^ (lc & 7)) * 8];
#pragma unroll
            for (int bt = 0; bt < 2; bt++) {
                bf16x8 bw = *(const bf16x8*)&wsel[(size_t)(bt*16 + lc) * 256 + kk*32 + lg*8];
                acc[bt] = MFMA16(a, bw, acc[bt], 0, 0, 0);
            }
        }
        if (w < 4) {
#pragma unroll
            for (int bt = 0; bt < 2; bt++) {
                float bias = bsel[bt*16 + lc] * bscale;
#pragma unroll
                for (int r = 0; r < 4; r++) {
                    int n = n0 + nch*16 + lg*4 + r;
                    fbuf[((size_t)b * N_ + n) * D_ + bt*16 + lc] = f2bf(acc[bt][r] + bias);
                }
            }
        } else {
#pragma unroll
            for (int bt = 0; bt < 2; bt++) {
                float bias = bsel[bt*16 + lc];
                int dk = bt*16 + lc;
#pragma unroll
                for (int r = 0; r < 4; r++) {
                    int n = n0 + nch*16 + lg*4 + r;
                    size_t off = ((size_t)b*128 + (n>>5))*1024 + (size_t)(n&31)*32
                               + ((((dk>>3)&3) ^ ((n>>1)&3)) << 3) + (dk&7);
                    gbuf[off] = f2bf(acc[bt][r] + bias);
                }
            }
        }
    }

    {
        const int cw = w * 32;
        f32x4 acch[2][4];
#pragma unroll
        for (int ct = 0; ct < 2; ct++)
#pragma unroll
            for (int nt = 0; nt < 4; nt++) acch[ct][nt] = zf;
#pragma unroll
        for (int kk = 0; kk < 8; kk++) {
            bf16x8 ah[2];
#pragma unroll
            for (int ct = 0; ct < 2; ct++)
                ah[ct] = *(const bf16x8*)&whb[(size_t)(cw + ct*16 + lc) * 256 + kk*32 + lg*8];
#pragma unroll
            for (int nt = 0; nt < 4; nt++) {
                bf16x8 bx = *(const bf16x8*)&xk[nt*16 + lc][((kk*4 + lg) ^ (lc & 7)) * 8];
#pragma unroll
                for (int ct = 0; ct < 2; ct++)
                    acch[ct][nt] = MFMA16(ah[ct], bx, acch[ct][nt], 0, 0, 0);
            }
        }
#pragma unroll
        for (int ct = 0; ct < 2; ct++)
#pragma unroll
            for (int r = 0; r < 4; r++) {
                int c = cw + ct*16 + lg*4 + r;
                float bias = pbh[c];
#pragma unroll
                for (int nt = 0; nt < 4; nt++) {
                    int n = n0 + nt*16 + lc;
                    size_t off = ((size_t)b*128 + (n>>5))*8192 + (size_t)c*32
                               + ((((n>>3)&3) ^ ((c>>1)&3)) << 3) + (n&7);
                    hbuf[off] = f2bf(acch[ct][nt][r] + bias);
                }
            }
    }
}

// ---------------- flash attention kernel (r17 tile-parity split + early-V hoist) ----------------
// grid 256 (b = blk&7, q0 = (blk>>3)*128), 512 threads = 8 waves:
// qw = w&3 (32 q-rows), par = w>>2 (tile parity). Wave (qw,par) processes tiles
// kt&1==par across ALL 256 channels. Static softmax (combinable tiles); denominator
// via ones-B MFMA; parity partials merged in epilogue. r17 pipeline: 8 LDS buffers,
// stage-at-window-start, vmcnt(12), 1 barrier/window.
// NEW (r20): K-fragments AND the first 2 ct's V-fragments (4 x b128, +16 VGPR) are
// read immediately after the barrier, ahead of QK -- removing the first V-read's
// ~120-150cy LDS latency from the post-pack serial chain (remaining 12 V-reads
// pipeline under the PV MFMA stream as before).
__global__ __launch_bounds__(512, 2)
void attn_kernel(const u16* __restrict__ fbuf, const u16* __restrict__ gbuf,
                 const u16* __restrict__ hbuf, const float* __restrict__ kvp,
                 const float* __restrict__ gamma_p, float* __restrict__ out)
{
    __shared__ __align__(16) u16 smem[8 * 9216];   // 8 x (V 16KB + K 2KB) = 144 KB

    const int b  = blockIdx.x & 7;
    const int q0 = (blockIdx.x >> 3) * 128;
    const int t  = threadIdx.x;
    const int w  = t >> 6;
    const int l  = t & 63;
    const int qw = w & 3;
    const int par = w >> 2;          // tile parity; waves w, w+4 share a SIMD
    const int lr = l & 31;
    const int b5 = l >> 5;
    const int sw = (lr >> 1) & 3;

    const u16* hb_t = hbuf + (size_t)b * 128 * 8192;
    const u16* gb_t = gbuf + (size_t)b * 128 * 1024;

    bf16x8 qf0, qf1;
    {
        const u16* fb = fbuf + ((size_t)b * N_ + q0 + qw*32 + lr) * D_;
        qf0 = *(const bf16x8*)(fb + b5*8);
        qf1 = *(const bf16x8*)(fb + 16 + b5*8);
    }

    bf16x8 ones;
    {
        union { u32 u[4]; bf16x8 v; } ov;
        ov.u[0] = 0x3F803F80u; ov.u[1] = 0x3F803F80u;
        ov.u[2] = 0x3F803F80u; ov.u[3] = 0x3F803F80u;
        ones = ov.v;
    }

    const f32x16 zf16 = {0,0,0,0, 0,0,0,0, 0,0,0,0, 0,0,0,0};
    f32x16 o_acc[8] = {zf16, zf16, zf16, zf16, zf16, zf16, zf16, zf16};
    f32x16 o_den = zf16;             // per-parity denominator (ones-B MFMA)

    const int koff0 = lr*32 + (((0|b5) ^ sw) << 3);
    const int koff1 = lr*32 + (((2|b5) ^ sw) << 3);
    const int vbase = lr*32;         // all 256 channels: + ct*1024 + vph
    const int vph0  = ((0|b5) ^ sw) << 3;
    const int vph1  = ((2|b5) ^ sw) << 3;

    auto stage = [&](int nb, int kt) {
        const u16* sv = hb_t + (size_t)kt*8192 + t*8;
        u16* dv = smem + nb*9216 + t*8;
        gload16(sv, dv);
        gload16(sv + 4096, dv + 4096);
        gload4(gb_t + (size_t)kt*1024 + t*2, smem + nb*9216 + 8192 + t*2);
    };

    // static softmax: P = exp2(s) in place, pack to bf16 A-fragments (r13-validated)
    auto exp_pack = [&](f32x16& s, bf16x8* pa) {
#pragma unroll
        for (int i = 0; i < 16; ++i) s[i] = fexp2(s[i]);
#pragma unroll
        for (int kc = 0; kc < 2; ++kc) {
            u32 d0, d1, e0, e1;
            { __hip_bfloat162 h2 = __float22bfloat162_rn(make_float2(s[8*kc+0], s[8*kc+1])); d0 = *(u32*)&h2; }
            { __hip_bfloat162 h2 = __float22bfloat162_rn(make_float2(s[8*kc+2], s[8*kc+3])); d1 = *(u32*)&h2; }
            { __hip_bfloat162 h2 = __float22bfloat162_rn(make_float2(s[8*kc+4], s[8*kc+5])); e0 = *(u32*)&h2; }
            { __hip_bfloat162 h2 = __float22bfloat162_rn(make_float2(s[8*kc+6], s[8*kc+7])); e1 = *(u32*)&h2; }
            asm("v_permlane32_swap_b32 %0, %1" : "+v"(d0), "+v"(e0));
            asm("v_permlane32_swap_b32 %0, %1" : "+v"(d1), "+v"(e1));
            union { u32 u[4]; bf16x8 v; } pk;
            pk.u[0] = d0; pk.u[1] = d1; pk.u[2] = e0; pk.u[3] = e1;
            pa[kc] = pk.v;
        }
    };

    stage(0, 0); stage(1, 1); stage(2, 2); stage(3, 3);   // 12 loads

    for (int p = 0; p < 64; ++p) {
        int ta = 2*p + 4; if (ta > 127) ta = 127;         // dummy re-stage in tail
        int tb = 2*p + 5; if (tb > 127) tb = 127;
        stage((2*p + 4) & 7, ta);
        stage((2*p + 5) & 7, tb);
        // wait tiles 2p,2p+1 (12 newer loads = tiles 2p+2..2p+5 stay in flight)
        asm volatile("s_waitcnt vmcnt(12)\n\ts_barrier" ::: "memory");

        const int kt = 2*p + par;                         // own-parity tile only
        const int nb = kt & 7;
        const u16* Kl = smem + nb*9216 + 8192;
        const u16* Vl = smem + nb*9216;

        // ---- hoisted reads: K + first 2 ct's V fragments (latency hides under QK/exp)
        bf16x8 kf0 = *(const bf16x8*)(Kl + koff0);
        bf16x8 kf1 = *(const bf16x8*)(Kl + koff1);
        bf16x8 vh[4];
        vh[0] = *(const bf16x8*)(Vl + vbase + 0*1024 + vph0);
        vh[1] = *(const bf16x8*)(Vl + vbase + 0*1024 + vph1);
        vh[2] = *(const bf16x8*)(Vl + vbase + 1*1024 + vph0);
        vh[3] = *(const bf16x8*)(Vl + vbase + 1*1024 + vph1);

        __builtin_amdgcn_s_setprio(1);
        f32x16 s = MFMA32(kf0, qf0, zf16, 0, 0, 0);
        s = MFMA32(kf1, qf1, s, 0, 0, 0);
        __builtin_amdgcn_s_setprio(0);

        bf16x8 pa[2];
        exp_pack(s, pa);

        __builtin_amdgcn_s_setprio(1);
        o_den = MFMA32(pa[0], ones, o_den, 0, 0, 0);
        o_den = MFMA32(pa[1], ones, o_den, 0, 0, 0);
        // ct 0-1 from hoisted registers (no post-pack LDS latency)
        o_acc[0] = MFMA32(pa[0], vh[0], o_acc[0], 0, 0, 0);
        o_acc[0] = MFMA32(pa[1], vh[1], o_acc[0], 0, 0, 0);
        o_acc[1] = MFMA32(pa[0], vh[2], o_acc[1], 0, 0, 0);
        o_acc[1] = MFMA32(pa[1], vh[3], o_acc[1], 0, 0, 0);
#pragma unroll
        for (int ct = 2; ct < 8; ++ct) {
            bf16x8 v0 = *(const bf16x8*)(Vl + vbase + ct*1024 + vph0);
            bf16x8 v1 = *(const bf16x8*)(Vl + vbase + ct*1024 + vph1);
            o_acc[ct] = MFMA32(pa[0], v0, o_acc[ct], 0, 0, 0);
            o_acc[ct] = MFMA32(pa[1], v1, o_acc[ct], 0, 0, 0);
        }
        __builtin_amdgcn_s_setprio(0);
    }

    // ---- epilogue (drain dummy prefetches before reusing smem)
    asm volatile("s_waitcnt vmcnt(0)" ::: "memory");
    const float gmm = gamma_p[0];

    // l-exchange across parity: lbuf [2 par][4 qw][64 lane][16 g] f32 = 32 KB
    float* lbuf = (float*)smem;
    {
        float* myl = lbuf + (((par*4 + qw)*64 + l) * 16);
        *(f32x4*)(myl +  0) = (f32x4){o_den[0],  o_den[1],  o_den[2],  o_den[3]};
        *(f32x4*)(myl +  4) = (f32x4){o_den[4],  o_den[5],  o_den[6],  o_den[7]};
        *(f32x4*)(myl +  8) = (f32x4){o_den[8],  o_den[9],  o_den[10], o_den[11]};
        *(f32x4*)(myl + 12) = (f32x4){o_den[12], o_den[13], o_den[14], o_den[15]};
    }
    __syncthreads();
    float linv[16];
    {
        const float* pl = lbuf + ((((par^1)*4 + qw)*64 + l) * 16);
#pragma unroll
        for (int g = 0; g < 16; ++g) linv[g] = gmm / (o_den[g] + pl[g]);
    }

    float* o_trA = (float*)smem;          // [64 c][132 q] f32 = 33792 B
    float* o_trB = o_trA + 64*132;        // parity-1 partial
    for (int cc = 0; cc < 4; ++cc) {
        __syncthreads();                   // also separates lbuf reads from o_trA writes
        float* buf = par ? o_trB : o_trA;
#pragma unroll
        for (int ci = 0; ci < 2; ++ci) {
            int ct = cc*2 + ci;
#pragma unroll
            for (int g = 0; g < 16; ++g) {
                int q_loc = (g & 3) + 8*(g >> 2) + b5*4;
                buf[(ci*32 + lr)*132 + qw*32 + q_loc] = o_acc[ct][g] * linv[g];
            }
        }
        __syncthreads();
        int c_loc = t >> 3, j = t & 7;
        int c = cc*64 + c_loc;
        size_t base = ((size_t)b*CV_ + c)*N_ + q0 + j*16;
        const float* oa = o_trA + c_loc*132 + j*16;
        const float* ob = o_trB + c_loc*132 + j*16;
#pragma unroll
        for (int u = 0; u < 4; ++u) {
            float4 kvv = *(const float4*)(kvp + base + u*4);
            float4 rs;
            rs.x = oa[u*4+0] + ob[u*4+0] + kvv.x;
            rs.y = oa[u*4+1] + ob[u*4+1] + kvv.y;
            rs.z = oa[u*4+2] + ob[u*4+2] + kvv.z;
            rs.w = oa[u*4+3] + ob[u*4+3] + kvv.w;
            *(float4*)(out + base + u*4) = rs;
        }
    }
}

extern "C" void kernel_launch(void* const* d_in, const int* in_sizes, int n_in,
                              void* d_out, int out_size, void* d_ws, size_t ws_size,
                              hipStream_t stream)
{
    const float* q     = (const float*)d_in[0];
    const float* kv    = (const float*)d_in[1];
    const float* Wf    = (const float*)d_in[2];
    const float* pbf   = (const float*)d_in[3];
    const float* Wg    = (const float*)d_in[4];
    const float* pbg   = (const float*)d_in[5];
    const float* Wh    = (const float*)d_in[6];
    const float* pbh   = (const float*)d_in[7];
    const float* gamma = (const float*)d_in[8];
    float* out = (float*)d_out;

    u16* wfb  = (u16*)d_ws;
    u16* wgb  = wfb + 8192;
    u16* whb  = wgb + 8192;
    u16* fbuf = whb + 65536;
    u16* gbuf = fbuf + (size_t)B_ * N_ * D_;
    u16* hbuf = gbuf + (size_t)B_ * N_ * D_;

    wcvt_kernel<<<dim3(80), dim3(256), 0, stream>>>(Wf, Wg, Wh, wfb, wgb, whb);
    proj_kernel<<<dim3(512), dim3(512), 0, stream>>>(q, kv, wfb, pbf, wgb, pbg, whb, pbh,
                                                     fbuf, gbuf, hbuf);
    attn_kernel<<<dim3(256), dim3(512), 0, stream>>>(fbuf, gbuf, hbuf, kv, gamma, out);
}